// Round 7
// baseline (135.008 us; speedup 1.0000x reference)
//
#include <hip/hip_runtime.h>

// Chamfer 2D exact NN, B=4, N=M=8192.
// Out (flat f32): dist1[32768] | dist2[32768] | idx1[32768] | idx2[32768]
//
// R7: TWO dispatches (was 3 + queue):
//  1) bucketize (8 blocks): LDS-resident counting-sort into 1024 x-buckets
//     (exact-float edges XLO + k*XW), linear coalesced writeback. R6-validated.
//  2) window_scan: 64 queries/block, qpos-centered 512-rank window staged in
//     LDS, 4 waves x 128-candidate chunks, lex (d,idx) min, exact-conservative
//     bucket-edge certification — and an INLINED block-cooperative brute-force
//     for the (rare) uncertified queries (no queue, no 3rd kernel, no gaps).
// Exactness: pair math __fmul_rn/__fadd_rn identical to reference rounding;
// lex (d, orig_idx) == np.argmin first occurrence; certification conservative
// under RN monotonicity; certified-or-brute => output exact and deterministic
// even though intra-bucket order (LDS atomics) is not.

#define NPTS 8192
#define NBUK 1024
#define XLO  (-6.0f)
#define XW   (0.01171875f)    // 12/1024 = 3*2^-8, exact; all edges exact floats
#define WIN  512
#define UNI  (WIN + 64)       // staged union per 64-query block

__device__ __forceinline__ int bucket_of(float x) {
    int k = (int)floorf((x - XLO) * (1.0f / XW));
    k = k < 0 ? 0 : (k > NBUK - 1 ? NBUK - 1 : k);
    // enforce: k>0 -> x >= XLO+k*XW ; k<NBUK-1 -> x < XLO+(k+1)*XW
#pragma unroll
    for (int it = 0; it < 3; ++it) {
        if (k < NBUK - 1 && x >= XLO + (float)(k + 1) * XW) k++;
        else if (k > 0 && x < XLO + (float)k * XW) k--;
    }
    return k;
}

// ---- 1) bucketize: 8 blocks (sb = set*4+b), 1024 threads, LDS-resident ----
__global__ __launch_bounds__(1024) void bucketize_kernel(
    const float* __restrict__ in1, const float* __restrict__ in2,
    float4* __restrict__ bpts)
{
    __shared__ float4 spts[NPTS];   // 128 KB sorted staging
    __shared__ int h[NBUK];         // counts -> exclusive starts -> cursors
    __shared__ int wsum[16];        // per-wave scan partials

    const int sb = blockIdx.x;
    const float2* __restrict__ src =
        (const float2*)(((sb >= 4) ? in2 : in1) + (size_t)(sb & 3) * NPTS * 2);
    const int t    = threadIdx.x;
    const int lane = t & 63;
    const int w    = t >> 6;

    h[t] = 0;                       // 1024 threads, 1024 bins
    __syncthreads();

    // pass 1: load 8 points/thread into registers, count buckets
    float px[8], py[8];
    int   pk[8];
#pragma unroll
    for (int i = 0; i < 8; ++i) {
        const float2 xy = src[t + (i << 10)];
        px[i] = xy.x; py[i] = xy.y;
        pk[i] = bucket_of(xy.x);
        atomicAdd(&h[pk[i]], 1);
    }
    __syncthreads();

    // exclusive prefix scan of h[1024]: wave shuffle scan + 16 partials
    const int v = h[t];
    int inc = v;
#pragma unroll
    for (int d = 1; d < 64; d <<= 1) {
        const int o = __shfl_up(inc, d, 64);
        if (lane >= d) inc += o;
    }
    if (lane == 63) wsum[w] = inc;
    __syncthreads();
    if (t < 16) {                    // wave 0 scans the 16 wave totals
        int pv = wsum[t];
        int pinc = pv;
#pragma unroll
        for (int d = 1; d < 16; d <<= 1) {
            const int o = __shfl_up(pinc, d, 64);
            if (lane >= d) pinc += o;
        }
        wsum[t] = pinc - pv;         // exclusive wave offset
    }
    __syncthreads();
    h[t] = (inc - v) + wsum[w];      // exclusive start == initial cursor
    __syncthreads();

    // pass 2: place into LDS at sorted positions (cheap LDS scatter).
#pragma unroll
    for (int i = 0; i < 8; ++i) {
        const int pos = atomicAdd(&h[pk[i]], 1);
        spts[pos] = make_float4(px[i], py[i], (float)(t + (i << 10)), 0.0f);
    }
    __syncthreads();

    // linear coalesced writeback
#pragma unroll
    for (int i = 0; i < 8; ++i)
        bpts[(size_t)sb * NPTS + t + (i << 10)] = spts[t + (i << 10)];
}

// ---- 2) window scan + inlined fallback: 1024 blocks, 64 queries/block -----
__global__ __launch_bounds__(256) void window_scan_kernel(
    const float4* __restrict__ bpts, const float* __restrict__ in1,
    const float* __restrict__ in2, float* __restrict__ out)
{
    __shared__ float4 win[UNI];          // 9216 B
    __shared__ float pbd[4][64];
    __shared__ float pbz[4][64];
    __shared__ unsigned long long failmask;

    const int bid = blockIdx.x;
    const int t   = threadIdx.x;
    const int q0slot = bid * 64;         // first qslot of block
    const int db  = q0slot >> 13;        // dir*4 + b  (64 | 8192: no straddle)
    const int dir = db >> 2;
    const int b   = db & 3;
    const int q0  = q0slot & 8191;
    const int qsb = (dir ? 4 : 0) + b;
    const int rsb = (dir ? 0 : 4) + b;

    const float4* __restrict__ Q  = bpts + (size_t)qsb * NPTS;
    const float4* __restrict__ Rf = bpts + (size_t)rsb * NPTS;

    int u0 = q0 - WIN / 2;
    u0 = u0 < 0 ? 0 : (u0 > NPTS - UNI ? NPTS - UNI : u0);

    // stage union [u0, u0+576): coalesced float4 loads
    win[t]       = Rf[u0 + t];
    win[t + 256] = Rf[u0 + 256 + t];
    if (t < UNI - 512) win[t + 512] = Rf[u0 + 512 + t];
    __syncthreads();

    const int s = t >> 6;                // wave id = candidate chunk
    const int L = t & 63;                // lane = query-in-block
    const int qpos = q0 + L;
    const float4 q = Q[qpos];
    const float qx = q.x, qy = q.y;

    int wl = qpos - WIN / 2;
    wl = wl < 0 ? 0 : (wl > NPTS - WIN ? NPTS - WIN : wl);
    const int base = (wl - u0) + (s << 7);   // lane-contiguous -> conflict-free

    // two independent lex-min chains over this wave's 128-candidate chunk
    float bd0 = 1e30f, bd1 = 1e30f, bz0 = 0.0f, bz1 = 0.0f;
    for (int i = 0; i < 128; i += 8) {
#pragma unroll
        for (int u = 0; u < 8; ++u) {
            const float4 r = win[base + i + u];
            const float dx = qx - r.x;
            const float dy = qy - r.y;
            // identical rounding to reference: (dx*dx)+(dy*dy), no FMA
            const float d = __fadd_rn(__fmul_rn(dx, dx), __fmul_rn(dy, dy));
            if (u & 1) {
                const bool c = (d < bd1) || (d == bd1 && r.z < bz1);
                bd1 = c ? d : bd1; bz1 = c ? r.z : bz1;
            } else {
                const bool c = (d < bd0) || (d == bd0 && r.z < bz0);
                bd0 = c ? d : bd0; bz0 = c ? r.z : bz0;
            }
        }
    }
    const bool cm = (bd1 < bd0) || (bd1 == bd0 && bz1 < bz0);
    pbd[s][L] = cm ? bd1 : bd0;
    pbz[s][L] = cm ? bz1 : bz0;
    __syncthreads();

    if (t < 64) {                        // wave 0: combine, certify, write
        float best = pbd[0][L];
        float bif  = pbz[0][L];
#pragma unroll
        for (int k = 1; k < 4; ++k) {
            const float dv = pbd[k][L];
            const float zv = pbz[k][L];
            const bool c = (dv < best) || (dv == best && zv < bif);
            best = c ? dv : best;
            bif  = c ? zv : bif;
        }

        // exact-conservative certification:
        //  left : all p<wl have x <= right_edge(bucket(x[wl-1])); that bucket
        //         is determined by POSITION wl-1 (deterministic), and
        //         d >= fl(dx^2) >= fl(dxe^2) > best => can't beat or tie.
        const int wr = wl + WIN;
        bool okL = (wl == 0), okR = (wr >= NPTS);
        if (!okL) {
            const int kl = bucket_of(Rf[wl - 1].x);
            if (kl < NBUK - 1) {
                const float dxe = qx - (XLO + (float)(kl + 1) * XW);
                okL = (dxe > 0.0f) && (__fmul_rn(dxe, dxe) > best);
            }
        }
        if (!okR) {
            const int kr = bucket_of(Rf[wr].x);
            if (kr > 0) {
                const float dxe = (XLO + (float)kr * XW) - qx;
                okR = (dxe > 0.0f) && (__fmul_rn(dxe, dxe) > best);
            }
        }

        const int qid = (int)q.z;
        const int od  = b * 8192 + qid;
        if (dir == 0) { out[od]         = best; out[65536 + od] = bif; }
        else          { out[32768 + od] = best; out[98304 + od] = bif; }

        const unsigned long long fm = __ballot(!(okL && okR));
        if (t == 0) failmask = fm;
    }
    __syncthreads();

    // ---- inlined fallback: all 256 threads brute-force each failing lane --
    unsigned long long fm = failmask;
    if (fm == 0ULL) return;
    // refs in ORIGINAL index order; per-thread j ascends -> strict < keeps
    // the first occurrence within a thread; cross-thread lex (d, idx) reduce.
    const float2* __restrict__ P =
        (const float2*)((dir ? in1 : in2) + (size_t)b * NPTS * 2);

    while (fm) {
        const int fl_ = __builtin_ctzll(fm);
        fm &= fm - 1ULL;
        const float4 fq = Q[q0 + fl_];       // broadcast load (L2-hot)
        const float fqx = fq.x, fqy = fq.y;

        float bd = 1e30f, bz = 0.0f;
#pragma unroll 4
        for (int j = t; j < NPTS; j += 256) {
            const float2 rp = P[j];
            const float dx = fqx - rp.x;
            const float dy = fqy - rp.y;
            const float d = __fadd_rn(__fmul_rn(dx, dx), __fmul_rn(dy, dy));
            const bool c = d < bd;
            bd = c ? d : bd;
            bz = c ? (float)j : bz;
        }
#pragma unroll
        for (int m = 1; m < 64; m <<= 1) {
            const float od = __shfl_xor(bd, m, 64);
            const float oz = __shfl_xor(bz, m, 64);
            const bool c = (od < bd) || (od == bd && oz < bz);
            bd = c ? od : bd;
            bz = c ? oz : bz;
        }
        if ((t & 63) == 0) { pbd[t >> 6][0] = bd; pbz[t >> 6][0] = bz; }
        __syncthreads();
        if (t == 0) {
            float fbd = pbd[0][0], fbz = pbz[0][0];
#pragma unroll
            for (int k = 1; k < 4; ++k) {
                const bool c = (pbd[k][0] < fbd) ||
                               (pbd[k][0] == fbd && pbz[k][0] < fbz);
                fbd = c ? pbd[k][0] : fbd;
                fbz = c ? pbz[k][0] : fbz;
            }
            const int qid = (int)fq.z;
            const int od  = b * 8192 + qid;
            if (dir == 0) { out[od]         = fbd; out[65536 + od] = fbz; }
            else          { out[32768 + od] = fbd; out[98304 + od] = fbz; }
        }
        __syncthreads();     // protect pbd/pbz before next failing query
    }
}

extern "C" void kernel_launch(void* const* d_in, const int* in_sizes, int n_in,
                              void* d_out, int out_size, void* d_ws, size_t ws_size,
                              hipStream_t stream) {
    const float* in1 = (const float*)d_in[0];
    const float* in2 = (const float*)d_in[1];
    float* out = (float*)d_out;
    (void)in_sizes; (void)n_in; (void)out_size; (void)ws_size;

    // ws layout: bpts 8*8192*16B = 1 MiB
    float4* bpts = (float4*)d_ws;

    bucketize_kernel<<<8, 1024, 0, stream>>>(in1, in2, bpts);
    window_scan_kernel<<<1024, 256, 0, stream>>>(bpts, in1, in2, out);
}

// Round 8
// 46.938 us; speedup vs baseline: 2.8763x; 2.8763x over previous
//
#include <hip/hip_runtime.h>

// Chamfer 2D exact NN, B=4, N=M=8192.
// Out (flat f32): dist1[32768] | dist2[32768] | idx1[32768] | idx2[32768]
//
// R8: three load-balanced dispatches (R7 showed inlined fallback = straggler
// disaster: 8% occupancy, 127us):
//  1) bucketize, 16 blocks: 8 blocks x-sort -> bpts, 8 blocks y-sort ->
//     ypts + ystarts. LDS-resident counting sort (R6-validated), linear
//     coalesced writeback.
//  2) x-window scan (R6-validated verbatim): 64 queries/block, 512-rank
//     window, lex (d,idx) min, exact-conservative x-edge certification;
//     fails -> global queue.
//  3) y-pass: ONE WAVE per queued query (2048 waves). 512-rank y-window scan
//     (64 lanes x 8 float4), combined with carried pass-1 best (re-read from
//     out), y-edge certification (sufficient alone: unscanned => y-gap >=
//     dye => d >= fl(dye^2) > best). Rare double-fails: same wave brute-forces
//     8192 idx-ordered points (validated pattern).
// Exactness: pair math __fmul_rn/__fadd_rn == reference rounding; final
// result always the exact global lex (d, orig_idx) min == np.argmin first
// occurrence; deterministic outputs despite nondeterministic bucket order.

#define NPTS 8192
#define NBUK 1024
#define XLO  (-6.0f)
#define XW   (0.01171875f)    // 12/1024 = 3*2^-8, exact; all edges exact floats
#define WIN  512
#define UNI  (WIN + 64)       // staged union per 64-query block

__device__ __forceinline__ int bucket_of(float x) {
    int k = (int)floorf((x - XLO) * (1.0f / XW));
    k = k < 0 ? 0 : (k > NBUK - 1 ? NBUK - 1 : k);
    // enforce: k>0 -> x >= XLO+k*XW ; k<NBUK-1 -> x < XLO+(k+1)*XW
#pragma unroll
    for (int it = 0; it < 3; ++it) {
        if (k < NBUK - 1 && x >= XLO + (float)(k + 1) * XW) k++;
        else if (k > 0 && x < XLO + (float)k * XW) k--;
    }
    return k;
}

// ---- 1) bucketize: 16 blocks (mode = bid>>3: 0 x-sort, 1 y-sort) ----------
__global__ __launch_bounds__(1024) void bucketize_kernel(
    const float* __restrict__ in1, const float* __restrict__ in2,
    float4* __restrict__ bpts, float4* __restrict__ ypts,
    int* __restrict__ ystarts, int* __restrict__ cnt)
{
    __shared__ float4 spts[NPTS];   // 128 KB sorted staging
    __shared__ int h[NBUK];         // counts -> exclusive starts -> cursors
    __shared__ int wsum[16];        // per-wave scan partials

    const int mode = blockIdx.x >> 3;          // 0: x-key, 1: y-key
    const int sb   = blockIdx.x & 7;           // set*4 + b
    const float2* __restrict__ src =
        (const float2*)(((sb >= 4) ? in2 : in1) + (size_t)(sb & 3) * NPTS * 2);
    const int t    = threadIdx.x;
    const int lane = t & 63;
    const int w    = t >> 6;

    h[t] = 0;
    if (blockIdx.x == 0 && t == 0) *cnt = 0;
    __syncthreads();

    // pass 1: load 8 points/thread into registers, count buckets
    float px[8], py[8];
    int   pk[8];
#pragma unroll
    for (int i = 0; i < 8; ++i) {
        const float2 xy = src[t + (i << 10)];
        px[i] = xy.x; py[i] = xy.y;
        pk[i] = bucket_of(mode ? xy.y : xy.x);
        atomicAdd(&h[pk[i]], 1);
    }
    __syncthreads();

    // exclusive prefix scan of h[1024]: wave shuffle scan + 16 partials
    const int v = h[t];
    int inc = v;
#pragma unroll
    for (int d = 1; d < 64; d <<= 1) {
        const int o = __shfl_up(inc, d, 64);
        if (lane >= d) inc += o;
    }
    if (lane == 63) wsum[w] = inc;
    __syncthreads();
    if (t < 16) {                    // wave 0 scans the 16 wave totals
        int pv = wsum[t];
        int pinc = pv;
#pragma unroll
        for (int d = 1; d < 16; d <<= 1) {
            const int o = __shfl_up(pinc, d, 64);
            if (lane >= d) pinc += o;
        }
        wsum[t] = pinc - pv;         // exclusive wave offset
    }
    __syncthreads();
    const int excl = (inc - v) + wsum[w];   // exclusive start
    h[t] = excl;
    if (mode) {
        ystarts[sb * (NBUK + 1) + t] = excl;
        if (t == 0) ystarts[sb * (NBUK + 1) + NBUK] = NPTS;
    }
    __syncthreads();

    // pass 2: place into LDS at sorted positions (cheap LDS scatter)
#pragma unroll
    for (int i = 0; i < 8; ++i) {
        const int pos = atomicAdd(&h[pk[i]], 1);
        spts[pos] = make_float4(px[i], py[i], (float)(t + (i << 10)), 0.0f);
    }
    __syncthreads();

    // linear coalesced writeback
    float4* __restrict__ dst = (mode ? ypts : bpts) + (size_t)sb * NPTS;
#pragma unroll
    for (int i = 0; i < 8; ++i)
        dst[t + (i << 10)] = spts[t + (i << 10)];
}

// ---- 2) x-window scan: 1024 blocks, 64 queries/block (R6-validated) -------
__global__ __launch_bounds__(256) void window_scan_kernel(
    const float4* __restrict__ bpts, float* __restrict__ out,
    int* __restrict__ cnt, int* __restrict__ queue)
{
    __shared__ float4 win[UNI];          // 9216 B
    __shared__ float pbd[4][64];
    __shared__ float pbz[4][64];

    const int bid = blockIdx.x;
    const int t   = threadIdx.x;
    const int q0slot = bid * 64;         // first qslot of block
    const int db  = q0slot >> 13;        // dir*4 + b  (64 | 8192: no straddle)
    const int dir = db >> 2;
    const int b   = db & 3;
    const int q0  = q0slot & 8191;
    const int qsb = (dir ? 4 : 0) + b;
    const int rsb = (dir ? 0 : 4) + b;

    const float4* __restrict__ Q  = bpts + (size_t)qsb * NPTS;
    const float4* __restrict__ Rf = bpts + (size_t)rsb * NPTS;

    int u0 = q0 - WIN / 2;
    u0 = u0 < 0 ? 0 : (u0 > NPTS - UNI ? NPTS - UNI : u0);

    // stage union [u0, u0+576): coalesced float4 loads
    win[t]       = Rf[u0 + t];
    win[t + 256] = Rf[u0 + 256 + t];
    if (t < UNI - 512) win[t + 512] = Rf[u0 + 512 + t];
    __syncthreads();

    const int s = t >> 6;                // wave id = candidate chunk
    const int L = t & 63;                // lane = query-in-block
    const int qpos = q0 + L;
    const float4 q = Q[qpos];
    const float qx = q.x, qy = q.y;

    int wl = qpos - WIN / 2;
    wl = wl < 0 ? 0 : (wl > NPTS - WIN ? NPTS - WIN : wl);
    const int base = (wl - u0) + (s << 7);   // lane-contiguous -> conflict-free

    // two independent lex-min chains over this wave's 128-candidate chunk
    float bd0 = 1e30f, bd1 = 1e30f, bz0 = 0.0f, bz1 = 0.0f;
    for (int i = 0; i < 128; i += 8) {
#pragma unroll
        for (int u = 0; u < 8; ++u) {
            const float4 r = win[base + i + u];
            const float dx = qx - r.x;
            const float dy = qy - r.y;
            // identical rounding to reference: (dx*dx)+(dy*dy), no FMA
            const float d = __fadd_rn(__fmul_rn(dx, dx), __fmul_rn(dy, dy));
            if (u & 1) {
                const bool c = (d < bd1) || (d == bd1 && r.z < bz1);
                bd1 = c ? d : bd1; bz1 = c ? r.z : bz1;
            } else {
                const bool c = (d < bd0) || (d == bd0 && r.z < bz0);
                bd0 = c ? d : bd0; bz0 = c ? r.z : bz0;
            }
        }
    }
    const bool cm = (bd1 < bd0) || (bd1 == bd0 && bz1 < bz0);
    pbd[s][L] = cm ? bd1 : bd0;
    pbz[s][L] = cm ? bz1 : bz0;
    __syncthreads();

    if (t < 64) {                        // wave 0: combine, certify, write
        float best = pbd[0][L];
        float bif  = pbz[0][L];
#pragma unroll
        for (int k = 1; k < 4; ++k) {
            const float dv = pbd[k][L];
            const float zv = pbz[k][L];
            const bool c = (dv < best) || (dv == best && zv < bif);
            best = c ? dv : best;
            bif  = c ? zv : bif;
        }

        // exact-conservative certification (x):
        //  all p<wl have x <= right_edge(bucket(x[wl-1])) and
        //  d >= fl(dx^2) >= fl(dxe^2) > best => can't beat or tie
        const int wr = wl + WIN;
        bool okL = (wl == 0), okR = (wr >= NPTS);
        if (!okL) {
            const int kl = bucket_of(Rf[wl - 1].x);
            if (kl < NBUK - 1) {
                const float dxe = qx - (XLO + (float)(kl + 1) * XW);
                okL = (dxe > 0.0f) && (__fmul_rn(dxe, dxe) > best);
            }
        }
        if (!okR) {
            const int kr = bucket_of(Rf[wr].x);
            if (kr > 0) {
                const float dxe = (XLO + (float)kr * XW) - qx;
                okR = (dxe > 0.0f) && (__fmul_rn(dxe, dxe) > best);
            }
        }

        const int qid = (int)q.z;
        const int od  = b * 8192 + qid;
        if (dir == 0) { out[od]         = best; out[65536 + od] = bif; }
        else          { out[32768 + od] = best; out[98304 + od] = bif; }

        if (!(okL && okR)) {
            const int pos = atomicAdd(cnt, 1);
            queue[pos] = q0slot + L;     // db*8192 + qpos
        }
    }
}

// ---- 3) y-pass: one wave per queued query (2048 waves) --------------------
__global__ __launch_bounds__(256) void ypass_kernel(
    const float4* __restrict__ bpts, const float4* __restrict__ ypts,
    const int* __restrict__ ystarts, const float* __restrict__ in1,
    const float* __restrict__ in2, const int* __restrict__ cnt,
    const int* __restrict__ queue, float* __restrict__ out)
{
    const int n    = *cnt;
    const int gw   = (blockIdx.x << 2) + (threadIdx.x >> 6);
    const int lane = threadIdx.x & 63;

    for (int item = gw; item < n; item += 2048) {
        const int qslot = queue[item];
        const int qpos  = qslot & 8191;
        const int db    = qslot >> 13;
        const int dir   = db >> 2;
        const int b     = db & 3;
        const int qsb   = (dir ? 4 : 0) + b;
        const int rsb   = (dir ? 0 : 4) + b;

        const float4 q = bpts[(size_t)qsb * NPTS + qpos];
        const float qx = q.x, qy = q.y;
        const int qid  = (int)q.z;
        const int od   = b * 8192 + qid;

        // carried pass-1 lex-min (over the x-window)
        float best = (dir == 0) ? out[od]         : out[32768 + od];
        float bif  = (dir == 0) ? out[65536 + od] : out[98304 + od];

        // y-rank window centered via ystarts
        const float4* __restrict__ Y  = ypts + (size_t)rsb * NPTS;
        const int* __restrict__ ys    = ystarts + rsb * (NBUK + 1);
        const int kq = bucket_of(qy);
        int wl = ((ys[kq] + ys[kq + 1]) >> 1) - WIN / 2;
        wl = wl < 0 ? 0 : (wl > NPTS - WIN ? NPTS - WIN : wl);

        // scan 512 y-ranked candidates: lane + 64*i, coalesced
        float bd = 1e30f, bz = 0.0f;
#pragma unroll
        for (int i = 0; i < 8; ++i) {
            const float4 r = Y[wl + lane + (i << 6)];
            const float dx = qx - r.x;
            const float dy = qy - r.y;
            const float d = __fadd_rn(__fmul_rn(dx, dx), __fmul_rn(dy, dy));
            const bool c = (d < bd) || (d == bd && r.z < bz);
            bd = c ? d : bd;
            bz = c ? r.z : bz;
        }
        // butterfly lex reduce -> all lanes hold the window min
#pragma unroll
        for (int m = 1; m < 64; m <<= 1) {
            const float od_ = __shfl_xor(bd, m, 64);
            const float oz_ = __shfl_xor(bz, m, 64);
            const bool c = (od_ < bd) || (od_ == bd && oz_ < bz);
            bd = c ? od_ : bd;
            bz = c ? oz_ : bz;
        }
        // combine with carried best
        {
            const bool c = (bd < best) || (bd == best && bz < bif);
            best = c ? bd : best;
            bif  = c ? bz : bif;
        }

        // y-edge certification (sufficient alone: any unscanned point p has
        // y-gap >= dye => d >= fl(dy^2) >= fl(dye^2) > best)
        const int wr = wl + WIN;
        bool okL = (wl == 0), okR = (wr >= NPTS);
        if (!okL) {
            const int kl = bucket_of(Y[wl - 1].y);
            if (kl < NBUK - 1) {
                const float dye = qy - (XLO + (float)(kl + 1) * XW);
                okL = (dye > 0.0f) && (__fmul_rn(dye, dye) > best);
            }
        }
        if (!okR) {
            const int kr = bucket_of(Y[wr].y);
            if (kr > 0) {
                const float dye = (XLO + (float)kr * XW) - qy;
                okR = (dye > 0.0f) && (__fmul_rn(dye, dye) > best);
            }
        }

        if (!(okL && okR)) {
            // double-fail: exact brute force over idx-ordered original array.
            // per-lane j ascends -> strict < keeps first occurrence in-lane.
            const float2* __restrict__ P =
                (const float2*)((dir ? in1 : in2) + (size_t)b * NPTS * 2);
            float fbd = 1e30f, fbz = 0.0f;
#pragma unroll 4
            for (int j = lane; j < NPTS; j += 64) {
                const float2 rp = P[j];
                const float dx = qx - rp.x;
                const float dy = qy - rp.y;
                const float d = __fadd_rn(__fmul_rn(dx, dx), __fmul_rn(dy, dy));
                const bool c = d < fbd;
                fbd = c ? d : fbd;
                fbz = c ? (float)j : fbz;
            }
#pragma unroll
            for (int m = 1; m < 64; m <<= 1) {
                const float od_ = __shfl_xor(fbd, m, 64);
                const float oz_ = __shfl_xor(fbz, m, 64);
                const bool c = (od_ < fbd) || (od_ == fbd && oz_ < fbz);
                fbd = c ? od_ : fbd;
                fbz = c ? oz_ : fbz;
            }
            best = fbd;
            bif  = fbz;
        }

        if (lane == 0) {
            if (dir == 0) { out[od]         = best; out[65536 + od] = bif; }
            else          { out[32768 + od] = best; out[98304 + od] = bif; }
        }
    }
}

extern "C" void kernel_launch(void* const* d_in, const int* in_sizes, int n_in,
                              void* d_out, int out_size, void* d_ws, size_t ws_size,
                              hipStream_t stream) {
    const float* in1 = (const float*)d_in[0];
    const float* in2 = (const float*)d_in[1];
    float* out = (float*)d_out;
    (void)in_sizes; (void)n_in; (void)out_size; (void)ws_size;

    // ws: bpts 1MiB | ypts 1MiB | ystarts 8*1025*4 | cnt 4 | queue 65536*4
    char* w = (char*)d_ws;
    float4* bpts = (float4*)w;
    float4* ypts = (float4*)(w + (size_t)8 * NPTS * sizeof(float4));
    int* ystarts = (int*)(w + (size_t)16 * NPTS * sizeof(float4));
    int* cnt     = ystarts + 8 * (NBUK + 1);
    int* queue   = cnt + 1;

    bucketize_kernel<<<16, 1024, 0, stream>>>(in1, in2, bpts, ypts, ystarts, cnt);
    window_scan_kernel<<<1024, 256, 0, stream>>>(bpts, out, cnt, queue);
    ypass_kernel<<<512, 256, 0, stream>>>(bpts, ypts, ystarts, in1, in2,
                                          cnt, queue, out);
}